// Round 11
// baseline (179.562 us; speedup 1.0000x reference)
//
#include <hip/hip_runtime.h>
#include <hip/hip_bf16.h>

// Problem constants
#define B_ 2
#define S_ 2048
#define DM_ 1024
#define TD_ 1024
#define H_ 16
#define HD_ 64

using bf16 = __hip_bfloat16;
typedef __attribute__((ext_vector_type(8))) short s8v;   // 8 bf16 = one MFMA A/B frag
typedef __attribute__((ext_vector_type(4))) float f4v;   // MFMA C/D frag

__device__ __forceinline__ f4v mfma_bf16(s8v a, s8v b, f4v c) {
    return __builtin_amdgcn_mfma_f32_16x16x32_bf16(a, b, c, 0, 0, 0);
}

// HW packed fp32x2 -> bf16x2 (RNE), single VOP3 instr on CDNA3/4
__device__ __forceinline__ unsigned cvt_pk_bf16(float a, float b) {
    unsigned r;
    asm("v_cvt_pk_bf16_f32 %0, %1, %2" : "=v"(r) : "v"(a), "v"(b));
    return r;
}
__device__ __forceinline__ int2 pack4bf(float a, float b, float c, float d) {
    int2 r;
    r.x = (int)cvt_pk_bf16(a, b);
    r.y = (int)cvt_pk_bf16(c, d);
    return r;
}

// cos_q[0] == 1.0 exactly: fp32 word = 0x3F800000 (low16==0); bf16 pair != 0 low16.
__device__ __forceinline__ bool detect_f32(const unsigned int* __restrict__ cosw) {
    return (cosw[0] & 0xFFFFu) == 0u;
}

// async global -> LDS, 16 B per lane (HW: dst = wave-uniform base + lane*16)
__device__ __forceinline__ void gload_lds16(const bf16* g, void* l) {
    __builtin_amdgcn_global_load_lds(
        (const __attribute__((address_space(1))) unsigned int*)(const void*)g,
        (__attribute__((address_space(3))) unsigned int*)l,
        16, 0, 0);
}

#define NQ_  (B_ * S_ * DM_)
#define NWI_ (3 * TD_ * DM_)
#define NWO_ (DM_ * TD_)
#define NCVT_BLOCKS ((NQ_ + NWI_ + NWO_) / 2048)   // 4096

// ---------------------------------------------------------------------------
// Fused prep: blocks [0,4096) convert (query|W_in|W_out) -> bf16;
// blocks 4096..4097 compute lengths[b] from the mask (4-way storage detect).
// ---------------------------------------------------------------------------
__global__ __launch_bounds__(256)
void prep_all(const void* __restrict__ q, const void* __restrict__ wi,
              const void* __restrict__ wo, bf16* __restrict__ dst,
              const void* __restrict__ mask, int* __restrict__ lengths,
              const unsigned int* __restrict__ cosw) {
    const int bid = blockIdx.x;
    if (bid < NCVT_BLOCKS) {
        const bool f32 = detect_f32(cosw);
        int i = (bid * 256 + threadIdx.x) * 8;
        const void* src; int off;
        if (i < NQ_)              { src = q;  off = i; }
        else if (i < NQ_ + NWI_)  { src = wi; off = i - NQ_; }
        else                      { src = wo; off = i - NQ_ - NWI_; }
        if (f32) {
            const float* p = (const float*)src + off;
            float4 x = *reinterpret_cast<const float4*>(p);
            float4 y = *reinterpret_cast<const float4*>(p + 4);
            union { unsigned u[4]; int4 v; } t;
            t.u[0] = cvt_pk_bf16(x.x, x.y);
            t.u[1] = cvt_pk_bf16(x.z, x.w);
            t.u[2] = cvt_pk_bf16(y.x, y.y);
            t.u[3] = cvt_pk_bf16(y.z, y.w);
            *reinterpret_cast<int4*>(dst + i) = t.v;
        } else {
            *reinterpret_cast<int4*>(dst + i) =
                *reinterpret_cast<const int4*>((const bf16*)src + off);
        }
        return;
    }
    // lengths path
    int b = bid - NCVT_BLOCKS;
    unsigned int w0 = ((const unsigned int*)mask)[0];
    int enc;                 // 0=i32, 1=u8, 2=bf16, 3=f32
    if (w0 == 1u) enc = 0;
    else if (w0 == 0x01010101u) enc = 1;
    else if (w0 == 0x3F803F80u) enc = 2;
    else enc = 3;
    int cnt = 0;
    for (int s = threadIdx.x; s < S_; s += 256) {
        int i = b * S_ + s;
        bool v;
        if (enc == 0)      v = ((const int*)mask)[i] != 0;
        else if (enc == 1) v = ((const unsigned char*)mask)[i] != 0;
        else if (enc == 2) v = ((const unsigned short*)mask)[i] != 0;
        else               v = ((const float*)mask)[i] != 0.f;
        cnt += v ? 1 : 0;
    }
    __shared__ int red[256];
    red[threadIdx.x] = cnt;
    __syncthreads();
    for (int off = 128; off > 0; off >>= 1) {
        if (threadIdx.x < off) red[threadIdx.x] += red[threadIdx.x + off];
        __syncthreads();
    }
    if (threadIdx.x == 0) lengths[b] = red[0];
}

// ---------------------------------------------------------------------------
// Output-projection NT GEMM, BM=128 x BN=64 tile (512 blocks -> 2 blocks/CU,
// 2 waves/SIMD: one block's MFMA hides the other's staging). Proven R5 form.
// Wave covers 64m x 32n: acc[4][2] (32 AGPRs). XCD-clustered bid swizzle.
// c_dyn: 1 -> write detected dtype (fp32 if inputs fp32), 0 -> bf16.
// ---------------------------------------------------------------------------
__global__ __launch_bounds__(256, 4)
void gemm_out(const bf16* __restrict__ A, const bf16* __restrict__ Bm,
              void* __restrict__ C, int M, int N, int K,
              int c_dyn, const unsigned int* __restrict__ cosw) {
    __shared__ bf16 lds_a[128 * 64];   // 16 KB, [row][chunk^(row&7)]
    __shared__ bf16 lds_b[64 * 64];    //  8 KB

    const bool cf32 = c_dyn && detect_f32(cosw);

    const int t = threadIdx.x;
    const int wave = t >> 6, lane = t & 63;
    const int quad = lane >> 4, l16 = lane & 15;
    const int wm = wave >> 1, wn = wave & 1;
    // bijective XCD-clustered decode: 512 blocks = 8 XCD x (4 m x 16 n)
    const int bid = blockIdx.x;
    const int c = bid & 7, g = bid >> 3;            // g: 0..63
    const int m0 = (c * 4 + (g & 3)) * 128;         // m_panel 0..31
    const int n0 = (g >> 2) * 64;                   // n_idx 0..15
    const int wuni = __builtin_amdgcn_readfirstlane(wave);

    f4v acc[4][2];
    #pragma unroll
    for (int i = 0; i < 4; i++)
        #pragma unroll
        for (int j = 0; j < 2; j++)
            acc[i][j] = f4v{0.f, 0.f, 0.f, 0.f};

    for (int k0 = 0; k0 < K; k0 += 64) {
        __syncthreads();                 // prior reads done before restage
        #pragma unroll
        for (int i = 0; i < 4; i++) {
            int ci = i * 256 + t;        // A chunks 0..1023 (16B each)
            int row = ci >> 3;
            int csrc = (ci & 7) ^ (row & 7);
            gload_lds16(A + (size_t)(m0 + row) * K + k0 + csrc * 8,
                        (char*)lds_a + i * 4096 + wuni * 1024);
        }
        #pragma unroll
        for (int i = 0; i < 2; i++) {
            int ci = i * 256 + t;        // B chunks 0..511
            int row = ci >> 3;
            int csrc = (ci & 7) ^ (row & 7);
            gload_lds16(Bm + (size_t)(n0 + row) * K + k0 + csrc * 8,
                        (char*)lds_b + i * 4096 + wuni * 1024);
        }
        __syncthreads();                 // drains vmcnt -> staged data visible

        #pragma unroll
        for (int kk = 0; kk < 2; kk++) {
            s8v afr[4], bfr[2];
            #pragma unroll
            for (int mb = 0; mb < 4; mb++) {
                int r = wm * 64 + mb * 16 + l16;
                int ch = (kk * 4 + quad) ^ (l16 & 7);
                afr[mb] = *reinterpret_cast<const s8v*>(&lds_a[r * 64 + ch * 8]);
            }
            #pragma unroll
            for (int nb = 0; nb < 2; nb++) {
                int r = wn * 32 + nb * 16 + l16;
                int ch = (kk * 4 + quad) ^ (l16 & 7);
                bfr[nb] = *reinterpret_cast<const s8v*>(&lds_b[r * 64 + ch * 8]);
            }
            // swapped: D[i=n-in-16][j=m-in-16], lane j=l16, regs i=quad*4+rr
            #pragma unroll
            for (int mb = 0; mb < 4; mb++)
                #pragma unroll
                for (int nb = 0; nb < 2; nb++)
                    acc[mb][nb] = mfma_bf16(bfr[nb], afr[mb], acc[mb][nb]);
        }
    }

    // epilogue: m = m0+wm*64+mb*16+l16 (per lane), n = n0+wn*32+nb*16+quad*4+rr
    #pragma unroll
    for (int mb = 0; mb < 4; mb++) {
        int m = m0 + wm * 64 + mb * 16 + l16;
        #pragma unroll
        for (int nb = 0; nb < 2; nb++) {
            int n = n0 + wn * 32 + nb * 16 + quad * 4;
            f4v v = acc[mb][nb];
            if (cf32) {
                *reinterpret_cast<f4v*>(&((float*)C)[(size_t)m * N + n]) = v;
            } else {
                *reinterpret_cast<int2*>(&((bf16*)C)[(size_t)m * N + n]) =
                    pack4bf(v[0], v[1], v[2], v[3]);
            }
        }
    }
}

// ---------------------------------------------------------------------------
// QKV GEMM with FUSED RoPE + layout epilogue. R5 structure (128x128 tile,
// 2-barrier K-step, XCD-clustered grid 768) but __launch_bounds__(256, 4):
// cap regs at 128/wave (64 acc AGPR + <=64 VGPR; was 72+64=136 at lb(,3)).
// If the allocator shaves the 8 VGPRs, occupancy rises 3 -> 4 waves/SIMD
// (12 -> 16 waves/CU) and the per-step vmcnt(0)+barrier drain (~900 cyc of
// exposed HBM latency; R10 counters: MfmaUtil 22% = 480/2150 cyc/step) gets
// one more co-resident block to hide under. LDS 32 KB x 4 = 128 <= 160 OK.
// Epilogue-only spills acceptable. R6 (m-split) and R7 (dbuf) regressed;
// this is the remaining unexplored occupancy lever at unchanged work/wave.
// Region by n0: [0,1024) Q, [1024,2048) K, [2048,3072) V.
// ---------------------------------------------------------------------------
__global__ __launch_bounds__(256, 4)
void gemm_qkv(const bf16* __restrict__ A, const bf16* __restrict__ Bm,
              bf16* __restrict__ Qh, bf16* __restrict__ Kt, bf16* __restrict__ Vt,
              const void* __restrict__ sin_t, const void* __restrict__ cos_t) {
    __shared__ bf16 lds_a[128 * 64];   // 16 KB, [row][chunk^(row&7)]
    __shared__ bf16 lds_b[128 * 64];

    const int t = threadIdx.x;
    const int wave = t >> 6, lane = t & 63;
    const int quad = lane >> 4, l16 = lane & 15;
    const int wm = wave >> 1, wn = wave & 1;
    // bijective XCD-clustered decode: 768 blocks = 8 XCD x (4 m x 24 n)
    const int bid = blockIdx.x;
    const int c = bid & 7, g = bid >> 3;            // g: 0..95
    const int m0 = (c * 4 + (g & 3)) * 128;         // m_panel 0..31
    const int n0 = (g >> 2) * 128;                  // n_panel 0..23
    const int wuni = __builtin_amdgcn_readfirstlane(wave);

    f4v acc[4][4];
    #pragma unroll
    for (int i = 0; i < 4; i++)
        #pragma unroll
        for (int j = 0; j < 4; j++)
            acc[i][j] = f4v{0.f, 0.f, 0.f, 0.f};

    for (int k0 = 0; k0 < 1024; k0 += 64) {
        __syncthreads();
        #pragma unroll
        for (int i = 0; i < 4; i++) {
            int ci = i * 256 + t;
            int row = ci >> 3;
            int csrc = (ci & 7) ^ (row & 7);
            gload_lds16(A + (size_t)(m0 + row) * 1024 + k0 + csrc * 8,
                        (char*)lds_a + i * 4096 + wuni * 1024);
            gload_lds16(Bm + (size_t)(n0 + row) * 1024 + k0 + csrc * 8,
                        (char*)lds_b + i * 4096 + wuni * 1024);
        }
        __syncthreads();

        #pragma unroll
        for (int kk = 0; kk < 2; kk++) {
            s8v afr[4], bfr[4];
            #pragma unroll
            for (int mb = 0; mb < 4; mb++) {
                int r = wm * 64 + mb * 16 + l16;
                int ch = (kk * 4 + quad) ^ (l16 & 7);
                afr[mb] = *reinterpret_cast<const s8v*>(&lds_a[r * 64 + ch * 8]);
            }
            #pragma unroll
            for (int nb = 0; nb < 4; nb++) {
                int r = wn * 64 + nb * 16 + l16;
                int ch = (kk * 4 + quad) ^ (l16 & 7);
                bfr[nb] = *reinterpret_cast<const s8v*>(&lds_b[r * 64 + ch * 8]);
            }
            #pragma unroll
            for (int mb = 0; mb < 4; mb++)
                #pragma unroll
                for (int nb = 0; nb < 4; nb++)
                    acc[mb][nb] = mfma_bf16(bfr[nb], afr[mb], acc[mb][nb]);
        }
    }

    // ---- fused epilogue; n0 (wave-uniform) selects region ----
    const int region = n0 >> 10;             // 0=Q, 1=K, 2=V
    if (region < 2) {
        const bool f32 = detect_f32((const unsigned int*)cos_t);
        #pragma unroll
        for (int mb = 0; mb < 4; mb++) {
            const int m = m0 + wm * 64 + mb * 16 + l16;
            const int b = m >> 11, s = m & 2047;
            #pragma unroll
            for (int nb = 0; nb < 4; nb++) {
                const int n = n0 + wn * 64 + nb * 16 + quad * 4;
                const int d = n & 63;                 // = nb*16 + quad*4
                const int h = (n >> 6) & 15;
                const float sgn = (nb < 2) ? -1.f : 1.f;
                f4v v  = acc[mb][nb];
                f4v vp = acc[mb][nb ^ 2];             // partner (d+32)&63, same lane
                float cs[4], sn[4];
                if (f32) {
                    float4 c4 = *reinterpret_cast<const float4*>(
                        (const float*)cos_t + s * 64 + d);
                    float4 s4 = *reinterpret_cast<const float4*>(
                        (const float*)sin_t + s * 64 + d);
                    cs[0] = c4.x; cs[1] = c4.y; cs[2] = c4.z; cs[3] = c4.w;
                    sn[0] = s4.x; sn[1] = s4.y; sn[2] = s4.z; sn[3] = s4.w;
                } else {
                    const bf16* cp = (const bf16*)cos_t + s * 64 + d;
                    const bf16* sp = (const bf16*)sin_t + s * 64 + d;
                    #pragma unroll
                    for (int r = 0; r < 4; r++) {
                        cs[r] = __bfloat162float(cp[r]);
                        sn[r] = __bfloat162float(sp[r]);
                    }
                }
                float y[4];
                #pragma unroll
                for (int r = 0; r < 4; r++)
                    y[r] = v[r] * cs[r] + sgn * vp[r] * sn[r];
                if (region == 0) {
                    // Q: pre-scale 1/8 * log2(e) for exp2-based softmax
                    size_t o = ((size_t)(b * H_ + h) * S_ + s) * 64 + d;
                    *reinterpret_cast<int2*>(&Qh[o]) =
                        pack4bf(y[0] * 0.180336880f, y[1] * 0.180336880f,
                                y[2] * 0.180336880f, y[3] * 0.180336880f);
                } else {
                    size_t kt = ((size_t)(b * H_ + h) * 32 + (s >> 6)) * 4096;
                    int dp = ((((d >> 3) ^ (s & 7)) << 3) | (d & 7));
                    *reinterpret_cast<int2*>(&Kt[kt + (s & 63) * 64 + dp]) =
                        pack4bf(y[0], y[1], y[2], y[3]);
                }
            }
        }
    } else {
        // V: 128x128 LDS transpose. lds_a = rows 0..63, lds_b = rows 64..127
        // of the [key][d] tile (row stride 128, chunk-XOR swizzled by row&7).
        __syncthreads();                     // all MFMA-phase reads complete
        bf16* half_w = (wm == 0) ? lds_a : lds_b;   // wm picks row half
        #pragma unroll
        for (int mb = 0; mb < 4; mb++) {
            const int slr = mb * 16 + l16;           // row within half (0..63)
            #pragma unroll
            for (int nb = 0; nb < 4; nb++) {
                const int nl = wn * 64 + nb * 16 + quad * 4;  // local d 0..127
                f4v v = acc[mb][nb];
                // slr&7 == (wm*64+slr)&7: swizzle consistent across halves
                int off = (((nl >> 3) ^ (slr & 7)) << 3) | (nl & 7);
                *reinterpret_cast<int2*>(&half_w[slr * 128 + off]) =
                    pack4bf(v[0], v[1], v[2], v[3]);
            }
        }
        __syncthreads();
        const int b  = m0 >> 11;
        const int h0 = (n0 - 2048) >> 6;
        const int r0 = t & 7;                        // per-lane read rotation
        #pragma unroll
        for (int i = 0; i < 8; i++) {
            int id  = i * 256 + t;                   // 0..2047 int4 outputs
            int kc  = id & 7;                        // key 8-chunk
            int d   = (id >> 3) & 63;
            int sbl = (id >> 9) & 1;                 // which 64-key subtile
            int hh  = id >> 10;                      // which head half
            int cb  = (hh << 3) | (d >> 3);          // base LDS chunk of nl
            const short* half_r = reinterpret_cast<const short*>(
                sbl ? lds_b : lds_a);
            union { short s_[8]; int4 v4; } u;
            #pragma unroll
            for (int j = 0; j < 8; j++) {
                int e   = (j + r0) & 7;
                int slr = kc * 8 + e;                // row within half; slr&7==e
                u.s_[e] = half_r[slr * 128 + (((cb ^ e) << 3) | (d & 7))];
            }
            size_t tb = ((size_t)(b * H_ + h0 + hh) * 32 +
                         ((m0 & 2047) >> 6) + sbl) * 4096;
            *reinterpret_cast<int4*>(&Vt[tb + d * 64 + ((kc ^ (d & 7)) << 3)]) = u.v4;
        }
    }
}

// ---------------------------------------------------------------------------
// Flash attention v9: R5-proven skeleton (CAUSAL PAIRING 512 blocks, uniform
// 33 iters, perfect 2-blocks/CU makespan; 2-buffer staging; plain
// __syncthreads; setprio around MFMA clusters) + ONES-MFMA ROW-SUM:
// row-sum rides the (14%-idle) MFMA pipe instead of 16 serial VALU fadds,
// and the end-of-pass shfl_xor quad-reduction is gone (MFMA reduces across
// quads). Numerator/denominator use identical bf16 P. Proven R10: best total.
// ---------------------------------------------------------------------------
__global__ __launch_bounds__(256)
void attn_fused(const bf16* __restrict__ Qh, const bf16* __restrict__ Kt,
                const bf16* __restrict__ Vt, const int* __restrict__ lengths,
                bf16* __restrict__ out) {
    __shared__ bf16 k_buf[2 * 4096];   // K tiles  [row(key)][chunk^(key&7)]
    __shared__ bf16 v_buf[2 * 4096];   // Vt tiles [row(d)][keychunk^(d&7)]
    __shared__ bf16 lds_p[4 * 16 * 72];// per-wave P tile [qrow][key]

    const int t = threadIdx.x, wave = t >> 6, lane = t & 63;
    const int quad = lane >> 4, l16 = lane & 15;
    // XCD-clustered decode: 512 blocks, 64 slots/XCD = 4 bh x 16 pairs
    const int bid = blockIdx.x;
    const int slot = bid >> 3;                    // 0..63
    const int bh = (bid & 7) * 4 + (slot >> 4);   // all of a bh on one XCD
    const int p = slot & 15;                      // pair index
    const int b = bh >> 4, h = bh & 15;

    const size_t hb = (size_t)bh * S_ * 64;          // Qh base
    const bf16* Ktp = Kt + (size_t)bh * 32 * 4096;   // tile array base
    const bf16* Vtp = Vt + (size_t)bh * 32 * 4096;
    const int wuni = __builtin_amdgcn_readfirstlane(wave);
    int len_raw = lengths[b];
    const int len_b = len_raw < 1 ? 1 : (len_raw > S_ ? S_ : len_raw);
    const int nkt_len = (len_b + 63) >> 6;

    // all-ones bf16 A-operand for the row-sum MFMA
    s8v ones;
    #pragma unroll
    for (int i = 0; i < 8; i++) ones[i] = (short)0x3F80;

    #pragma unroll
    for (int pass = 0; pass < 2; pass++) {
        const int qb = pass ? (31 - p) : p;
        const int qrow_g = qb * 64 + wave * 16 + l16;   // this lane's q-row
        const int kmax = (qrow_g < len_b - 1) ? qrow_g : (len_b - 1);

        s8v qf[2];
        {
            const bf16* qptr = Qh + hb + (size_t)qrow_g * 64 + quad * 8;
            qf[0] = *reinterpret_cast<const s8v*>(qptr);
            qf[1] = *reinterpret_cast<const s8v*>(qptr + 32);
        }

        f4v o_acc[4];
        #pragma unroll
        for (int a = 0; a < 4; a++) o_acc[a] = f4v{0.f, 0.f, 0.f, 0.f};
        f4v l_acc = f4v{0.f, 0.f, 0.f, 0.f};   // row-sum via ones-MFMA

        const int nkt = (qb + 1) < nkt_len ? (qb + 1) : nkt_len;

        f4v s_prev[4];
        auto process_tile = [&](int pt, const bf16* vb) {
            const int pbase = pt * 64;
            const bool tail = (pt == qb) || (pbase + 64 > len_b);  // uniform
            #pragma unroll
            for (int a = 0; a < 4; a++) {
                float e0[4];
                #pragma unroll
                for (int r = 0; r < 4; r++) {
                    float e = __builtin_amdgcn_exp2f(s_prev[a][r]);
                    if (tail) {
                        int key = pbase + a * 16 + quad * 4 + r;
                        e = (key <= kmax) ? e : 0.f;
                    }
                    e0[r] = e;
                }
                *reinterpret_cast<int2*>(
                    &lds_p[(wave * 16 + l16) * 72 + a * 16 + quad * 4]) =
                    pack4bf(e0[0], e0[1], e0[2], e0[3]);
            }
            // wave-local: P writes -> P reads (lds_p region is per-wave)
            asm volatile("s_waitcnt lgkmcnt(0)" ::: "memory");
            __builtin_amdgcn_s_setprio(1);
            #pragma unroll
            for (int kk = 0; kk < 2; kk++) {
                s8v pf = *reinterpret_cast<const s8v*>(
                    &lds_p[(wave * 16 + l16) * 72 + kk * 32 + quad * 8]);
                l_acc = mfma_bf16(ones, pf, l_acc);   // row sum on MFMA pipe
                #pragma unroll
                for (int a = 0; a < 4; a++) {
                    int ch = (kk * 4 + quad) ^ (l16 & 7);
                    s8v vf = *reinterpret_cast<const s8v*>(
                        &vb[(a * 16 + l16) * 64 + ch * 8]);
                    o_acc[a] = mfma_bf16(vf, pf, o_acc[a]);
                }
            }
            __builtin_amdgcn_s_setprio(0);
        };

        // prologue: stage K[0] (pass-0 drain reads only v_buf/lds_p; no race)
        #pragma unroll
        for (int i = 0; i < 2; i++) {
            int ci = i * 256 + t;
            gload_lds16(Ktp + ci * 8, (char*)k_buf + i * 4096 + wuni * 1024);
        }
        __syncthreads();   // K[0] resident (drains vmcnt)

        for (int kt = 0; kt < nkt; kt++) {
            const int cur = kt & 1;
            // stage V[kt] -> vbuf[cur] (one tile behind K)
            {
                const bf16* vst = Vtp + (size_t)kt * 4096;
                #pragma unroll
                for (int i = 0; i < 2; i++) {
                    int ci = i * 256 + t;
                    gload_lds16(vst + ci * 8,
                                (char*)v_buf + cur * 8192 + i * 4096 + wuni * 1024);
                }
            }
            // stage K[kt+1] -> kbuf[cur^1]
            if (kt + 1 < nkt) {
                const bf16* kst = Ktp + (size_t)(kt + 1) * 4096;
                #pragma unroll
                for (int i = 0; i < 2; i++) {
                    int ci = i * 256 + t;
                    gload_lds16(kst + ci * 8,
                                (char*)k_buf + (cur ^ 1) * 8192 + i * 4096 + wuni * 1024);
                }
            }

            // S^T[kt] = K Q^T : lane holds (key = a*16+quad*4+r, qrow = l16)
            const bf16* kb = k_buf + cur * 4096;
            f4v s_acc[4];
            #pragma unroll
            for (int a = 0; a < 4; a++) s_acc[a] = f4v{0.f, 0.f, 0.f, 0.f};
            __builtin_amdgcn_s_setprio(1);
            #pragma unroll
            for (int kk = 0; kk < 2; kk++) {
                #pragma unroll
                for (int a = 0; a < 4; a++) {
                    int ch = (kk * 4 + quad) ^ (l16 & 7);
                    s8v kf = *reinterpret_cast<const s8v*>(
                        &kb[(a * 16 + l16) * 64 + ch * 8]);
                    s_acc[a] = mfma_bf16(kf, qf[kk], s_acc[a]);
                }
            }
            __builtin_amdgcn_s_setprio(0);

            // overlap: previous tile's exp/pack/PV under this tile's S-MFMA
            if (kt > 0) process_tile(kt - 1, v_buf + ((kt - 1) & 1) * 4096);

            #pragma unroll
            for (int a = 0; a < 4; a++) s_prev[a] = s_acc[a];

            __syncthreads();   // V[kt], K[kt+1] staged; LDS reads done before reuse
        }
        // drain: last tile
        process_tile(nkt - 1, v_buf + ((nkt - 1) & 1) * 4096);

        // l_acc[0] already holds the FULL row sum for qrow (MFMA reduced
        // across all 64 keys/tile and all quads) -- no shuffle needed.
        float inv_l = 1.f / l_acc[0];
        size_t orow = ((size_t)(b * S_ + qrow_g)) * TD_ + h * 64;
        #pragma unroll
        for (int a = 0; a < 4; a++) {
            *reinterpret_cast<int2*>(&out[orow + a * 16 + quad * 4]) =
                pack4bf(o_acc[a][0] * inv_l, o_acc[a][1] * inv_l,
                        o_acc[a][2] * inv_l, o_acc[a][3] * inv_l);
        }
    }
}

// ---------------------------------------------------------------------------
extern "C" void kernel_launch(void* const* d_in, const int* in_sizes, int n_in,
                              void* d_out, int out_size, void* d_ws, size_t ws_size,
                              hipStream_t stream) {
    const void* query = d_in[0];   // [B,S,DM]  fp32 (auto-detected, bf16-safe)
    const void* W_in  = d_in[1];   // [3TD,DM]
    const void* W_out = d_in[2];   // [DM,TD]
    const void* sin_q = d_in[3];   // [S,HD]
    const void* cos_q = d_in[4];   // [S,HD]   dtype probe
    const void* mask  = d_in[5];   // [B,S] bool, storage auto-detected
    const unsigned int* cosw = (const unsigned int*)cos_q;

    const size_t nQ  = NQ_;   // 4194304
    const size_t nWi = NWI_;  // 3145728
    const size_t nWo = NWO_;  // 1048576

    // Workspace layout (no aliasing hazards: gemm_qkv reads qbf/wibf and
    // writes Qh/Kt/Vt; attn reads Qh/Kt/Vt and writes attn; all disjoint).
    bf16* base = (bf16*)d_ws;
    bf16* attn = base;                               // [4096,1024] attn out
    bf16* Vt   = base + (size_t)4096 * 1024;         // tiled+swizzled V
    bf16* Qh   = base + (size_t)2 * 4096 * 1024;     // [B,H,S,64] linear
    bf16* Kt   = Qh + nQ;                            // tiled+swizzled K
    bf16* qbf  = Kt + nQ;                            // query bf16
    bf16* wibf = qbf + nQ;
    bf16* wobf = wibf + nWi;
    int* lengths = (int*)(wobf + nWo);

    prep_all<<<NCVT_BLOCKS + B_, 256, 0, stream>>>(
        query, W_in, W_out, qbf, mask, lengths, cosw);

    gemm_qkv<<<768, 256, 0, stream>>>(qbf, wibf, Qh, Kt, Vt, sin_q, cos_q);

    attn_fused<<<512, 256, 0, stream>>>(Qh, Kt, Vt, lengths, attn);

    gemm_out<<<512, 256, 0, stream>>>(attn, wobf, d_out, 4096, 1024, 1024, 1, cosw);
}

// Round 13
// 175.393 us; speedup vs baseline: 1.0238x; 1.0238x over previous
//
#include <hip/hip_runtime.h>
#include <hip/hip_bf16.h>

// Problem constants
#define B_ 2
#define S_ 2048
#define DM_ 1024
#define TD_ 1024
#define H_ 16
#define HD_ 64

using bf16 = __hip_bfloat16;
typedef __attribute__((ext_vector_type(8))) short s8v;   // 8 bf16 = one MFMA A/B frag
typedef __attribute__((ext_vector_type(4))) float f4v;   // MFMA C/D frag

__device__ __forceinline__ f4v mfma_bf16(s8v a, s8v b, f4v c) {
    return __builtin_amdgcn_mfma_f32_16x16x32_bf16(a, b, c, 0, 0, 0);
}

// HW packed fp32x2 -> bf16x2 (RNE), single VOP3 instr on CDNA3/4
__device__ __forceinline__ unsigned cvt_pk_bf16(float a, float b) {
    unsigned r;
    asm("v_cvt_pk_bf16_f32 %0, %1, %2" : "=v"(r) : "v"(a), "v"(b));
    return r;
}
__device__ __forceinline__ int2 pack4bf(float a, float b, float c, float d) {
    int2 r;
    r.x = (int)cvt_pk_bf16(a, b);
    r.y = (int)cvt_pk_bf16(c, d);
    return r;
}

// cos_q[0] == 1.0 exactly: fp32 word = 0x3F800000 (low16==0); bf16 pair != 0 low16.
__device__ __forceinline__ bool detect_f32(const unsigned int* __restrict__ cosw) {
    return (cosw[0] & 0xFFFFu) == 0u;
}

// async global -> LDS, 16 B per lane (HW: dst = wave-uniform base + lane*16)
__device__ __forceinline__ void gload_lds16(const bf16* g, void* l) {
    __builtin_amdgcn_global_load_lds(
        (const __attribute__((address_space(1))) unsigned int*)(const void*)g,
        (__attribute__((address_space(3))) unsigned int*)l,
        16, 0, 0);
}

#define NQ_  (B_ * S_ * DM_)
#define NWI_ (3 * TD_ * DM_)
#define NWO_ (DM_ * TD_)
#define NCVT_BLOCKS ((NQ_ + NWI_ + NWO_) / 2048)   // 4096

// ---------------------------------------------------------------------------
// Fused prep: blocks [0,4096) convert (query|W_in|W_out) -> bf16;
// blocks 4096..4097 compute lengths[b] from the mask (4-way storage detect).
// ---------------------------------------------------------------------------
__global__ __launch_bounds__(256)
void prep_all(const void* __restrict__ q, const void* __restrict__ wi,
              const void* __restrict__ wo, bf16* __restrict__ dst,
              const void* __restrict__ mask, int* __restrict__ lengths,
              const unsigned int* __restrict__ cosw) {
    const int bid = blockIdx.x;
    if (bid < NCVT_BLOCKS) {
        const bool f32 = detect_f32(cosw);
        int i = (bid * 256 + threadIdx.x) * 8;
        const void* src; int off;
        if (i < NQ_)              { src = q;  off = i; }
        else if (i < NQ_ + NWI_)  { src = wi; off = i - NQ_; }
        else                      { src = wo; off = i - NQ_ - NWI_; }
        if (f32) {
            const float* p = (const float*)src + off;
            float4 x = *reinterpret_cast<const float4*>(p);
            float4 y = *reinterpret_cast<const float4*>(p + 4);
            union { unsigned u[4]; int4 v; } t;
            t.u[0] = cvt_pk_bf16(x.x, x.y);
            t.u[1] = cvt_pk_bf16(x.z, x.w);
            t.u[2] = cvt_pk_bf16(y.x, y.y);
            t.u[3] = cvt_pk_bf16(y.z, y.w);
            *reinterpret_cast<int4*>(dst + i) = t.v;
        } else {
            *reinterpret_cast<int4*>(dst + i) =
                *reinterpret_cast<const int4*>((const bf16*)src + off);
        }
        return;
    }
    // lengths path
    int b = bid - NCVT_BLOCKS;
    unsigned int w0 = ((const unsigned int*)mask)[0];
    int enc;                 // 0=i32, 1=u8, 2=bf16, 3=f32
    if (w0 == 1u) enc = 0;
    else if (w0 == 0x01010101u) enc = 1;
    else if (w0 == 0x3F803F80u) enc = 2;
    else enc = 3;
    int cnt = 0;
    for (int s = threadIdx.x; s < S_; s += 256) {
        int i = b * S_ + s;
        bool v;
        if (enc == 0)      v = ((const int*)mask)[i] != 0;
        else if (enc == 1) v = ((const unsigned char*)mask)[i] != 0;
        else if (enc == 2) v = ((const unsigned short*)mask)[i] != 0;
        else               v = ((const float*)mask)[i] != 0.f;
        cnt += v ? 1 : 0;
    }
    __shared__ int red[256];
    red[threadIdx.x] = cnt;
    __syncthreads();
    for (int off = 128; off > 0; off >>= 1) {
        if (threadIdx.x < off) red[threadIdx.x] += red[threadIdx.x + off];
        __syncthreads();
    }
    if (threadIdx.x == 0) lengths[b] = red[0];
}

// ---------------------------------------------------------------------------
// Output-projection NT GEMM, BM=128 x BN=64 tile (512 blocks -> 2 blocks/CU,
// 2 waves/SIMD: one block's MFMA hides the other's staging). Proven R5 form.
// Wave covers 64m x 32n: acc[4][2] (32 AGPRs). XCD-clustered bid swizzle.
// c_dyn: 1 -> write detected dtype (fp32 if inputs fp32), 0 -> bf16.
// ---------------------------------------------------------------------------
__global__ __launch_bounds__(256, 4)
void gemm_out(const bf16* __restrict__ A, const bf16* __restrict__ Bm,
              void* __restrict__ C, int M, int N, int K,
              int c_dyn, const unsigned int* __restrict__ cosw) {
    __shared__ bf16 lds_a[128 * 64];   // 16 KB, [row][chunk^(row&7)]
    __shared__ bf16 lds_b[64 * 64];    //  8 KB

    const bool cf32 = c_dyn && detect_f32(cosw);

    const int t = threadIdx.x;
    const int wave = t >> 6, lane = t & 63;
    const int quad = lane >> 4, l16 = lane & 15;
    const int wm = wave >> 1, wn = wave & 1;
    // bijective XCD-clustered decode: 512 blocks = 8 XCD x (4 m x 16 n)
    const int bid = blockIdx.x;
    const int c = bid & 7, g = bid >> 3;            // g: 0..63
    const int m0 = (c * 4 + (g & 3)) * 128;         // m_panel 0..31
    const int n0 = (g >> 2) * 64;                   // n_idx 0..15
    const int wuni = __builtin_amdgcn_readfirstlane(wave);

    f4v acc[4][2];
    #pragma unroll
    for (int i = 0; i < 4; i++)
        #pragma unroll
        for (int j = 0; j < 2; j++)
            acc[i][j] = f4v{0.f, 0.f, 0.f, 0.f};

    for (int k0 = 0; k0 < K; k0 += 64) {
        __syncthreads();                 // prior reads done before restage
        #pragma unroll
        for (int i = 0; i < 4; i++) {
            int ci = i * 256 + t;        // A chunks 0..1023 (16B each)
            int row = ci >> 3;
            int csrc = (ci & 7) ^ (row & 7);
            gload_lds16(A + (size_t)(m0 + row) * K + k0 + csrc * 8,
                        (char*)lds_a + i * 4096 + wuni * 1024);
        }
        #pragma unroll
        for (int i = 0; i < 2; i++) {
            int ci = i * 256 + t;        // B chunks 0..511
            int row = ci >> 3;
            int csrc = (ci & 7) ^ (row & 7);
            gload_lds16(Bm + (size_t)(n0 + row) * K + k0 + csrc * 8,
                        (char*)lds_b + i * 4096 + wuni * 1024);
        }
        __syncthreads();                 // drains vmcnt -> staged data visible

        #pragma unroll
        for (int kk = 0; kk < 2; kk++) {
            s8v afr[4], bfr[2];
            #pragma unroll
            for (int mb = 0; mb < 4; mb++) {
                int r = wm * 64 + mb * 16 + l16;
                int ch = (kk * 4 + quad) ^ (l16 & 7);
                afr[mb] = *reinterpret_cast<const s8v*>(&lds_a[r * 64 + ch * 8]);
            }
            #pragma unroll
            for (int nb = 0; nb < 2; nb++) {
                int r = wn * 32 + nb * 16 + l16;
                int ch = (kk * 4 + quad) ^ (l16 & 7);
                bfr[nb] = *reinterpret_cast<const s8v*>(&lds_b[r * 64 + ch * 8]);
            }
            // swapped: D[i=n-in-16][j=m-in-16], lane j=l16, regs i=quad*4+rr
            #pragma unroll
            for (int mb = 0; mb < 4; mb++)
                #pragma unroll
                for (int nb = 0; nb < 2; nb++)
                    acc[mb][nb] = mfma_bf16(bfr[nb], afr[mb], acc[mb][nb]);
        }
    }

    // epilogue: m = m0+wm*64+mb*16+l16 (per lane), n = n0+wn*32+nb*16+quad*4+rr
    #pragma unroll
    for (int mb = 0; mb < 4; mb++) {
        int m = m0 + wm * 64 + mb * 16 + l16;
        #pragma unroll
        for (int nb = 0; nb < 2; nb++) {
            int n = n0 + wn * 32 + nb * 16 + quad * 4;
            f4v v = acc[mb][nb];
            if (cf32) {
                *reinterpret_cast<f4v*>(&((float*)C)[(size_t)m * N + n]) = v;
            } else {
                *reinterpret_cast<int2*>(&((bf16*)C)[(size_t)m * N + n]) =
                    pack4bf(v[0], v[1], v[2], v[3]);
            }
        }
    }
}

// ---------------------------------------------------------------------------
// QKV GEMM with FUSED RoPE + layout epilogue. PROVEN R10 FORM (42.2 us):
// 128x128 tile, 2-barrier K-step, lb(256,3), XCD-clustered grid 768.
// R6 (m-split), R7 (dbuf), R11 (lb(,4) reg-cap) all regressed -- local opt.
// Region by n0: [0,1024) Q, [1024,2048) K, [2048,3072) V.
// ---------------------------------------------------------------------------
__global__ __launch_bounds__(256, 3)
void gemm_qkv(const bf16* __restrict__ A, const bf16* __restrict__ Bm,
              bf16* __restrict__ Qh, bf16* __restrict__ Kt, bf16* __restrict__ Vt,
              const void* __restrict__ sin_t, const void* __restrict__ cos_t) {
    __shared__ bf16 lds_a[128 * 64];   // 16 KB, [row][chunk^(row&7)]
    __shared__ bf16 lds_b[128 * 64];

    const int t = threadIdx.x;
    const int wave = t >> 6, lane = t & 63;
    const int quad = lane >> 4, l16 = lane & 15;
    const int wm = wave >> 1, wn = wave & 1;
    // bijective XCD-clustered decode: 768 blocks = 8 XCD x (4 m x 24 n)
    const int bid = blockIdx.x;
    const int c = bid & 7, g = bid >> 3;            // g: 0..95
    const int m0 = (c * 4 + (g & 3)) * 128;         // m_panel 0..31
    const int n0 = (g >> 2) * 128;                  // n_panel 0..23
    const int wuni = __builtin_amdgcn_readfirstlane(wave);

    f4v acc[4][4];
    #pragma unroll
    for (int i = 0; i < 4; i++)
        #pragma unroll
        for (int j = 0; j < 4; j++)
            acc[i][j] = f4v{0.f, 0.f, 0.f, 0.f};

    for (int k0 = 0; k0 < 1024; k0 += 64) {
        __syncthreads();
        #pragma unroll
        for (int i = 0; i < 4; i++) {
            int ci = i * 256 + t;
            int row = ci >> 3;
            int csrc = (ci & 7) ^ (row & 7);
            gload_lds16(A + (size_t)(m0 + row) * 1024 + k0 + csrc * 8,
                        (char*)lds_a + i * 4096 + wuni * 1024);
            gload_lds16(Bm + (size_t)(n0 + row) * 1024 + k0 + csrc * 8,
                        (char*)lds_b + i * 4096 + wuni * 1024);
        }
        __syncthreads();

        #pragma unroll
        for (int kk = 0; kk < 2; kk++) {
            s8v afr[4], bfr[4];
            #pragma unroll
            for (int mb = 0; mb < 4; mb++) {
                int r = wm * 64 + mb * 16 + l16;
                int ch = (kk * 4 + quad) ^ (l16 & 7);
                afr[mb] = *reinterpret_cast<const s8v*>(&lds_a[r * 64 + ch * 8]);
            }
            #pragma unroll
            for (int nb = 0; nb < 4; nb++) {
                int r = wn * 64 + nb * 16 + l16;
                int ch = (kk * 4 + quad) ^ (l16 & 7);
                bfr[nb] = *reinterpret_cast<const s8v*>(&lds_b[r * 64 + ch * 8]);
            }
            #pragma unroll
            for (int mb = 0; mb < 4; mb++)
                #pragma unroll
                for (int nb = 0; nb < 4; nb++)
                    acc[mb][nb] = mfma_bf16(bfr[nb], afr[mb], acc[mb][nb]);
        }
    }

    // ---- fused epilogue; n0 (wave-uniform) selects region ----
    const int region = n0 >> 10;             // 0=Q, 1=K, 2=V
    if (region < 2) {
        const bool f32 = detect_f32((const unsigned int*)cos_t);
        #pragma unroll
        for (int mb = 0; mb < 4; mb++) {
            const int m = m0 + wm * 64 + mb * 16 + l16;
            const int b = m >> 11, s = m & 2047;
            #pragma unroll
            for (int nb = 0; nb < 4; nb++) {
                const int n = n0 + wn * 64 + nb * 16 + quad * 4;
                const int d = n & 63;                 // = nb*16 + quad*4
                const int h = (n >> 6) & 15;
                const float sgn = (nb < 2) ? -1.f : 1.f;
                f4v v  = acc[mb][nb];
                f4v vp = acc[mb][nb ^ 2];             // partner (d+32)&63, same lane
                float cs[4], sn[4];
                if (f32) {
                    float4 c4 = *reinterpret_cast<const float4*>(
                        (const float*)cos_t + s * 64 + d);
                    float4 s4 = *reinterpret_cast<const float4*>(
                        (const float*)sin_t + s * 64 + d);
                    cs[0] = c4.x; cs[1] = c4.y; cs[2] = c4.z; cs[3] = c4.w;
                    sn[0] = s4.x; sn[1] = s4.y; sn[2] = s4.z; sn[3] = s4.w;
                } else {
                    const bf16* cp = (const bf16*)cos_t + s * 64 + d;
                    const bf16* sp = (const bf16*)sin_t + s * 64 + d;
                    #pragma unroll
                    for (int r = 0; r < 4; r++) {
                        cs[r] = __bfloat162float(cp[r]);
                        sn[r] = __bfloat162float(sp[r]);
                    }
                }
                float y[4];
                #pragma unroll
                for (int r = 0; r < 4; r++)
                    y[r] = v[r] * cs[r] + sgn * vp[r] * sn[r];
                if (region == 0) {
                    // Q: pre-scale 1/8 * log2(e) for exp2-based softmax
                    size_t o = ((size_t)(b * H_ + h) * S_ + s) * 64 + d;
                    *reinterpret_cast<int2*>(&Qh[o]) =
                        pack4bf(y[0] * 0.180336880f, y[1] * 0.180336880f,
                                y[2] * 0.180336880f, y[3] * 0.180336880f);
                } else {
                    size_t kt = ((size_t)(b * H_ + h) * 32 + (s >> 6)) * 4096;
                    int dp = ((((d >> 3) ^ (s & 7)) << 3) | (d & 7));
                    *reinterpret_cast<int2*>(&Kt[kt + (s & 63) * 64 + dp]) =
                        pack4bf(y[0], y[1], y[2], y[3]);
                }
            }
        }
    } else {
        // V: 128x128 LDS transpose. lds_a = rows 0..63, lds_b = rows 64..127
        // of the [key][d] tile (row stride 128, chunk-XOR swizzled by row&7).
        __syncthreads();                     // all MFMA-phase reads complete
        bf16* half_w = (wm == 0) ? lds_a : lds_b;   // wm picks row half
        #pragma unroll
        for (int mb = 0; mb < 4; mb++) {
            const int slr = mb * 16 + l16;           // row within half (0..63)
            #pragma unroll
            for (int nb = 0; nb < 4; nb++) {
                const int nl = wn * 64 + nb * 16 + quad * 4;  // local d 0..127
                f4v v = acc[mb][nb];
                // slr&7 == (wm*64+slr)&7: swizzle consistent across halves
                int off = (((nl >> 3) ^ (slr & 7)) << 3) | (nl & 7);
                *reinterpret_cast<int2*>(&half_w[slr * 128 + off]) =
                    pack4bf(v[0], v[1], v[2], v[3]);
            }
        }
        __syncthreads();
        const int b  = m0 >> 11;
        const int h0 = (n0 - 2048) >> 6;
        const int r0 = t & 7;                        // per-lane read rotation
        #pragma unroll
        for (int i = 0; i < 8; i++) {
            int id  = i * 256 + t;                   // 0..2047 int4 outputs
            int kc  = id & 7;                        // key 8-chunk
            int d   = (id >> 3) & 63;
            int sbl = (id >> 9) & 1;                 // which 64-key subtile
            int hh  = id >> 10;                      // which head half
            int cb  = (hh << 3) | (d >> 3);          // base LDS chunk of nl
            const short* half_r = reinterpret_cast<const short*>(
                sbl ? lds_b : lds_a);
            union { short s_[8]; int4 v4; } u;
            #pragma unroll
            for (int j = 0; j < 8; j++) {
                int e   = (j + r0) & 7;
                int slr = kc * 8 + e;                // row within half; slr&7==e
                u.s_[e] = half_r[slr * 128 + (((cb ^ e) << 3) | (d & 7))];
            }
            size_t tb = ((size_t)(b * H_ + h0 + hh) * 32 +
                         ((m0 & 2047) >> 6) + sbl) * 4096;
            *reinterpret_cast<int4*>(&Vt[tb + d * 64 + ((kc ^ (d & 7)) << 3)]) = u.v4;
        }
    }
}

// ---------------------------------------------------------------------------
// Flash attention v10b: 8-WAVE WIDE Q-BLOCKS (QBLK=128), staging FIXED.
// R12 bug: Kt/Vt are ALREADY swizzled in global memory (gemm_qkv epilogue),
// so staging must be a LINEAR copy (thread t: src element t*8 -> LDS element
// t*8); R12 re-applied the XOR swizzle on the source = double-swizzle.
// 256 blocks x 512 threads; each staged K/V tile feeds 8 waves -> per-CU
// staging traffic and barrier count drop ~45% at identical MFMA work.
// CAUSAL SUPER-PAIRING: block handles sb = p and 15-p: uniform 34 iters,
// 256 blocks = exactly 1/CU (8 waves = 2/SIMD). Diag region pt >= 2*sb
// masked per-row by kmax (~3% wasted MFMA). ONES-MFMA row-sum kept (R10).
// LDS 50 KB.
// ---------------------------------------------------------------------------
__global__ __launch_bounds__(512)
void attn_fused(const bf16* __restrict__ Qh, const bf16* __restrict__ Kt,
                const bf16* __restrict__ Vt, const int* __restrict__ lengths,
                bf16* __restrict__ out) {
    __shared__ bf16 k_buf[2 * 4096];   // K tiles  [row(key)][chunk^(key&7)]
    __shared__ bf16 v_buf[2 * 4096];   // Vt tiles [row(d)][keychunk^(d&7)]
    __shared__ bf16 lds_p[8 * 16 * 72];// per-wave P tile [qrow][key]

    const int t = threadIdx.x, wave = t >> 6, lane = t & 63;
    const int quad = lane >> 4, l16 = lane & 15;
    // XCD-clustered decode: 256 blocks, 32 slots/XCD = 4 bh x 8 pairs
    const int bid = blockIdx.x;
    const int slot = bid >> 3;                    // 0..31
    const int bh = (bid & 7) * 4 + (slot >> 3);   // all of a bh on one XCD
    const int p = slot & 7;                       // pair index 0..7
    const int b = bh >> 4, h = bh & 15;

    const size_t hb = (size_t)bh * S_ * 64;          // Qh base
    const bf16* Ktp = Kt + (size_t)bh * 32 * 4096;   // tile array base
    const bf16* Vtp = Vt + (size_t)bh * 32 * 4096;
    const int wuni = __builtin_amdgcn_readfirstlane(wave);
    int len_raw = lengths[b];
    const int len_b = len_raw < 1 ? 1 : (len_raw > S_ ? S_ : len_raw);
    const int nkt_len = (len_b + 63) >> 6;

    // all-ones bf16 A-operand for the row-sum MFMA
    s8v ones;
    #pragma unroll
    for (int i = 0; i < 8; i++) ones[i] = (short)0x3F80;

    #pragma unroll
    for (int pass = 0; pass < 2; pass++) {
        const int sb = pass ? (15 - p) : p;          // q super-block (128 rows)
        const int qrow_g = sb * 128 + wave * 16 + l16;   // this lane's q-row
        const int kmax = (qrow_g < len_b - 1) ? qrow_g : (len_b - 1);

        s8v qf[2];
        {
            const bf16* qptr = Qh + hb + (size_t)qrow_g * 64 + quad * 8;
            qf[0] = *reinterpret_cast<const s8v*>(qptr);
            qf[1] = *reinterpret_cast<const s8v*>(qptr + 32);
        }

        f4v o_acc[4];
        #pragma unroll
        for (int a = 0; a < 4; a++) o_acc[a] = f4v{0.f, 0.f, 0.f, 0.f};
        f4v l_acc = f4v{0.f, 0.f, 0.f, 0.f};   // row-sum via ones-MFMA

        const int nkt_c = 2 * sb + 2;                // causal tiles for 128 rows
        const int nkt = nkt_c < nkt_len ? nkt_c : nkt_len;

        f4v s_prev[4];
        auto process_tile = [&](int pt, const bf16* vb) {
            const int pbase = pt * 64;
            const bool tail = (pt >= 2 * sb) || (pbase + 64 > len_b);  // uniform
            #pragma unroll
            for (int a = 0; a < 4; a++) {
                float e0[4];
                #pragma unroll
                for (int r = 0; r < 4; r++) {
                    float e = __builtin_amdgcn_exp2f(s_prev[a][r]);
                    if (tail) {
                        int key = pbase + a * 16 + quad * 4 + r;
                        e = (key <= kmax) ? e : 0.f;
                    }
                    e0[r] = e;
                }
                *reinterpret_cast<int2*>(
                    &lds_p[(wave * 16 + l16) * 72 + a * 16 + quad * 4]) =
                    pack4bf(e0[0], e0[1], e0[2], e0[3]);
            }
            // wave-local: P writes -> P reads (lds_p region is per-wave)
            asm volatile("s_waitcnt lgkmcnt(0)" ::: "memory");
            __builtin_amdgcn_s_setprio(1);
            #pragma unroll
            for (int kk = 0; kk < 2; kk++) {
                s8v pf = *reinterpret_cast<const s8v*>(
                    &lds_p[(wave * 16 + l16) * 72 + kk * 32 + quad * 8]);
                l_acc = mfma_bf16(ones, pf, l_acc);   // row sum on MFMA pipe
                #pragma unroll
                for (int a = 0; a < 4; a++) {
                    int ch = (kk * 4 + quad) ^ (l16 & 7);
                    s8v vf = *reinterpret_cast<const s8v*>(
                        &vb[(a * 16 + l16) * 64 + ch * 8]);
                    o_acc[a] = mfma_bf16(vf, pf, o_acc[a]);
                }
            }
            __builtin_amdgcn_s_setprio(0);
        };

        // prologue: stage K[0] LINEARLY (Kt pre-swizzled in global memory).
        // 512 threads x 16B = 8 KB = one tile in a single round; thread t's
        // LDS slot is element t*8, so source element must be t*8.
        gload_lds16(Ktp + t * 8, (char*)k_buf + wuni * 1024);
        __syncthreads();   // K[0] resident (drains vmcnt)

        for (int kt = 0; kt < nkt; kt++) {
            const int cur = kt & 1;
            // stage V[kt] -> vbuf[cur] (one tile behind K), linear copy
            gload_lds16(Vtp + (size_t)kt * 4096 + t * 8,
                        (char*)v_buf + cur * 8192 + wuni * 1024);
            // stage K[kt+1] -> kbuf[cur^1], linear copy
            if (kt + 1 < nkt) {
                gload_lds16(Ktp + (size_t)(kt + 1) * 4096 + t * 8,
                            (char*)k_buf + (cur ^ 1) * 8192 + wuni * 1024);
            }

            // S^T[kt] = K Q^T : lane holds (key = a*16+quad*4+r, qrow = l16)
            const bf16* kb = k_buf + cur * 4096;
            f4v s_acc[4];
            #pragma unroll
            for (int a = 0; a < 4; a++) s_acc[a] = f4v{0.f, 0.f, 0.f, 0.f};
            __builtin_amdgcn_s_setprio(1);
            #pragma unroll
            for (int kk = 0; kk < 2; kk++) {
                #pragma unroll
                for (int a = 0; a < 4; a++) {
                    int ch = (kk * 4 + quad) ^ (l16 & 7);
                    s8v kf = *reinterpret_cast<const s8v*>(
                        &kb[(a * 16 + l16) * 64 + ch * 8]);
                    s_acc[a] = mfma_bf16(kf, qf[kk], s_acc[a]);
                }
            }
            __builtin_amdgcn_s_setprio(0);

            // overlap: previous tile's exp/pack/PV under this tile's S-MFMA
            if (kt > 0) process_tile(kt - 1, v_buf + ((kt - 1) & 1) * 4096);

            #pragma unroll
            for (int a = 0; a < 4; a++) s_prev[a] = s_acc[a];

            __syncthreads();   // V[kt], K[kt+1] staged; LDS reads done before reuse
        }
        // drain: last tile
        process_tile(nkt - 1, v_buf + ((nkt - 1) & 1) * 4096);

        // l_acc[0] already holds the FULL row sum for qrow (MFMA reduced
        // across all 64 keys/tile and all quads) -- no shuffle needed.
        float inv_l = 1.f / l_acc[0];
        size_t orow = ((size_t)(b * S_ + qrow_g)) * TD_ + h * 64;
        #pragma unroll
        for (int a = 0; a < 4; a++) {
            *reinterpret_cast<int2*>(&out[orow + a * 16 + quad * 4]) =
                pack4bf(o_acc[a][0] * inv_l, o_acc[a][1] * inv_l,
                        o_acc[a][2] * inv_l, o_acc[a][3] * inv_l);
        }
    }
}

// ---------------------------------------------------------------------------
extern "C" void kernel_launch(void* const* d_in, const int* in_sizes, int n_in,
                              void* d_out, int out_size, void* d_ws, size_t ws_size,
                              hipStream_t stream) {
    const void* query = d_in[0];   // [B,S,DM]  fp32 (auto-detected, bf16-safe)
    const void* W_in  = d_in[1];   // [3TD,DM]
    const void* W_out = d_in[2];   // [DM,TD]
    const void* sin_q = d_in[3];   // [S,HD]
    const void* cos_q = d_in[4];   // [S,HD]   dtype probe
    const void* mask  = d_in[5];   // [B,S] bool, storage auto-detected
    const unsigned int* cosw = (const unsigned int*)cos_q;

    const size_t nQ  = NQ_;   // 4194304
    const size_t nWi = NWI_;  // 3145728
    const size_t nWo = NWO_;  // 1048576

    // Workspace layout (no aliasing hazards: gemm_qkv reads qbf/wibf and
    // writes Qh/Kt/Vt; attn reads Qh/Kt/Vt and writes attn; all disjoint).
    bf16* base = (bf16*)d_ws;
    bf16* attn = base;                               // [4096,1024] attn out
    bf16* Vt   = base + (size_t)4096 * 1024;         // tiled+swizzled V
    bf16* Qh   = base + (size_t)2 * 4096 * 1024;     // [B,H,S,64] linear
    bf16* Kt   = Qh + nQ;                            // tiled+swizzled K
    bf16* qbf  = Kt + nQ;                            // query bf16
    bf16* wibf = qbf + nQ;
    bf16* wobf = wibf + nWi;
    int* lengths = (int*)(wobf + nWo);

    prep_all<<<NCVT_BLOCKS + B_, 256, 0, stream>>>(
        query, W_in, W_out, qbf, mask, lengths, cosw);

    gemm_qkv<<<768, 256, 0, stream>>>(qbf, wibf, Qh, Kt, Vt, sin_q, cos_q);

    attn_fused<<<256, 512, 0, stream>>>(Qh, Kt, Vt, lengths, attn);

    gemm_out<<<512, 256, 0, stream>>>(attn, wobf, d_out, 4096, 1024, 1024, 1, cosw);
}